// Round 2
// baseline (622.665 us; speedup 1.0000x reference)
//
#include <hip/hip_runtime.h>

// out[b,t,h] = sum_{m<7} images[b,t,m] * A[m,h]
// images: (64,576,7) fp32   A: (4096,4096) fp32 (only first 7 rows used)
// out:    (64,576,4096) fp32  -- 604 MB pure write stream.
//
// R2: memcpy-shaped store stream. Each of 2048 persistent blocks owns a
// CONTIGUOUS 288 KB slice of out (18 consecutive rows x 16 KB) and writes it
// in ascending order, exactly like the 6.3 TB/s harness fill partitions its
// surface. To do that without A re-reads, all four 1024-col A windows live in
// registers (112 VGPRs, loaded once per block; ~3 waves/SIMD occupancy --
// 12 waves/CU x 24 outstanding 1KB stores is ample MLP for the HBM share).
// x coefficients are wave-uniform -> SGPR loads (42 dwords per 6-row group).

typedef float f4 __attribute__((ext_vector_type(4)));

#define NROWS  (64 * 576)   // 36864
#define HID    4096
#define MM     7
#define NW     4            // 4 windows x (256 thr x f4) = 4096 cols
#define BLOCKS 2048
#define RPB    18           // rows per block: 36864 / 2048, contiguous slice
#define SUB    6            // rows per x-load group (42 uniform dwords, no OOB tail)

__global__ __launch_bounds__(256, 3) void vt_kernel(const float* __restrict__ images,
                                                    const float* __restrict__ A,
                                                    float* __restrict__ out) {
    const int tid  = threadIdx.x;
    const int row0 = blockIdx.x * RPB;

    // All 4 column windows of A in registers: 28 x f4 = 112 VGPRs, one load per block.
    f4 a[NW][MM];
#pragma unroll
    for (int it = 0; it < NW; ++it) {
#pragma unroll
        for (int m = 0; m < MM; ++m) {
            a[it][m] = *(const f4*)(A + (size_t)m * HID + (it << 10) + (tid << 2));
        }
    }

    for (int g = 0; g < RPB / SUB; ++g) {
        const int r0 = row0 + g * SUB;

        // Wave-uniform coefficient block: 6 rows x 7 floats -> SGPRs.
        float x[SUB][MM];
#pragma unroll
        for (int r = 0; r < SUB; ++r) {
#pragma unroll
            for (int m = 0; m < MM; ++m) {
                x[r][m] = images[(size_t)(r0 + r) * MM + m];
            }
        }

        // Purely ascending store stream: row-major, window-minor.
        // 24 back-to-back 1KB wave-stores per group.
#pragma unroll
        for (int r = 0; r < SUB; ++r) {
            float* orow = out + (size_t)(r0 + r) * HID + (tid << 2);
#pragma unroll
            for (int it = 0; it < NW; ++it) {
                f4 acc = x[r][0] * a[it][0];
#pragma unroll
                for (int m = 1; m < MM; ++m) {
                    acc += x[r][m] * a[it][m];
                }
                *(f4*)(orow + (it << 10)) = acc;
            }
        }
    }
}

extern "C" void kernel_launch(void* const* d_in, const int* in_sizes, int n_in,
                              void* d_out, int out_size, void* d_ws, size_t ws_size,
                              hipStream_t stream) {
    const float* images = (const float*)d_in[0];
    const float* A      = (const float*)d_in[1];
    float* out          = (float*)d_out;

    vt_kernel<<<BLOCKS, 256, 0, stream>>>(images, A, out);
}